// Round 3
// baseline (165.068 us; speedup 1.0000x reference)
//
#include <hip/hip_runtime.h>
#include <math.h>

// Bit-exact replication of the numpy fp32 reference requires mul/add with
// separate rounding (no FMA contraction): the entry-face validity test
// (pos > -1) is knife-edge for every hitting ray.
#pragma clang fp contract(off)

#define DT 0.03125f
#define NSTEPS 111

__device__ __forceinline__ float4 lerp4(float4 a, float4 b, float w) {
#pragma clang fp contract(off)
    float wa = 1.0f - w;
    float4 r;
    r.x = a.x * wa + b.x * w;
    r.y = a.y * wa + b.y * w;
    r.z = a.z * wa + b.z * w;
    r.w = a.w * wa + b.w * w;
    return r;
}

// ---------------- repack: [B,4,D,H,W] -> [B,D,H,W,4] ----------------

// Fast path: 4 voxels per thread, float4 loads from each channel plane,
// 4x4 register transpose, 4 float4 stores. Requires spatial % 4 == 0.
__global__ __launch_bounds__(256) void repack4_kernel(const float* __restrict__ vol,
                                                      float4* __restrict__ out,
                                                      long spatial) {
    long q = (long)blockIdx.x * blockDim.x + threadIdx.x;
    long nq = spatial >> 2;
    if (q >= nq) return;
    long b = blockIdx.y;
    const float* p = vol + b * 4 * spatial + (q << 2);
    float4 c0 = *(const float4*)(p);
    float4 c1 = *(const float4*)(p + spatial);
    float4 c2 = *(const float4*)(p + 2 * spatial);
    float4 c3 = *(const float4*)(p + 3 * spatial);
    float4* o = out + b * spatial + (q << 2);
    o[0] = make_float4(c0.x, c1.x, c2.x, c3.x);
    o[1] = make_float4(c0.y, c1.y, c2.y, c3.y);
    o[2] = make_float4(c0.z, c1.z, c2.z, c3.z);
    o[3] = make_float4(c0.w, c1.w, c2.w, c3.w);
}

__global__ __launch_bounds__(256) void repack_kernel(const float* __restrict__ vol,
                                                     float4* __restrict__ out,
                                                     long total, long spatial) {
    long idx = (long)blockIdx.x * blockDim.x + threadIdx.x;
    if (idx >= total) return;
    long b = idx / spatial;
    long s = idx - b * spatial;
    const float* p = vol + b * 4 * spatial + s;
    float4 v;
    v.x = p[0];
    v.y = p[spatial];
    v.z = p[2 * spatial];
    v.w = p[3 * spatial];
    out[idx] = v;
}

// ---------------- ray march ----------------

__device__ __forceinline__ int voxel_base(float posx, float posy, float posz,
                                          int D, float gmax, int zstride,
                                          float& fx, float& fy, float& fz) {
#pragma clang fp contract(off)
    float gx = fminf(fmaxf((posx + 1.0f) * 0.5f * gmax, 0.0f), gmax);
    float gy = fminf(fmaxf((posy + 1.0f) * 0.5f * gmax, 0.0f), gmax);
    float gz = fminf(fmaxf((posz + 1.0f) * 0.5f * gmax, 0.0f), gmax);
    int ix0 = (int)floorf(gx); if (ix0 > D - 2) ix0 = D - 2;
    int iy0 = (int)floorf(gy); if (iy0 > D - 2) iy0 = D - 2;
    int iz0 = (int)floorf(gz); if (iz0 > D - 2) iz0 = D - 2;
    fx = gx - (float)ix0;
    fy = gy - (float)iy0;
    fz = gz - (float)iz0;
    return iz0 * zstride + iy0 * D + ix0;
}

__device__ __forceinline__ void load8(const float4* __restrict__ v4, int base,
                                      int D, int zstride, float4* c) {
    c[0] = v4[base];
    c[1] = v4[base + 1];
    c[2] = v4[base + D];
    c[3] = v4[base + D + 1];
    c[4] = v4[base + zstride];
    c[5] = v4[base + zstride + 1];
    c[6] = v4[base + zstride + D];
    c[7] = v4[base + zstride + D + 1];
}

__device__ __forceinline__ void accum_step(const float4* c, float fx, float fy, float fz,
                                           float& accr, float& accg, float& accb,
                                           float& alpha) {
#pragma clang fp contract(off)
    float4 c00 = lerp4(c[0], c[1], fx);
    float4 c01 = lerp4(c[2], c[3], fx);
    float4 c10 = lerp4(c[4], c[5], fx);
    float4 c11 = lerp4(c[6], c[7], fx);
    float4 c0 = lerp4(c00, c01, fy);
    float4 c1 = lerp4(c10, c11, fy);
    float4 samp = lerp4(c0, c1, fz);
    float contrib = fminf(alpha + samp.w * DT, 1.0f) - alpha;
    accr = accr + samp.x * contrib;
    accg = accg + samp.y * contrib;
    accb = accb + samp.z * contrib;
    alpha = alpha + contrib;
}

// Packed fast path: branch-free pipelined march over the precomputed valid range.
__global__ __launch_bounds__(256, 1) void raymarch_pipe_kernel(
        const float* __restrict__ camrot, const float* __restrict__ campos,
        const float* __restrict__ focal, const float* __restrict__ princpt,
        const float* __restrict__ pixelcoords, const float4* __restrict__ vol4,
        float* __restrict__ out, int B, int H, int W, int D) {
#pragma clang fp contract(off)
    int x = blockIdx.x * blockDim.x + threadIdx.x;
    int y = blockIdx.y * blockDim.y + threadIdx.y;
    int b = blockIdx.z;
    if (x >= W || y >= H) return;

    long pidx = (((long)b * H + y) * W + x) * 2;
    float px = pixelcoords[pidx];
    float py = pixelcoords[pidx + 1];
    const float* R = camrot + b * 9;
    float cpx = campos[b * 3 + 0], cpy = campos[b * 3 + 1], cpz = campos[b * 3 + 2];
    float flx = focal[b * 2 + 0], fly = focal[b * 2 + 1];
    float prx = princpt[b * 2 + 0], pry = princpt[b * 2 + 1];

    float rx = (px - prx) / flx;
    float ry = (py - pry) / fly;
    float rz = 1.0f;
    float dx = R[0] * rx + R[3] * ry + R[6] * rz;
    float dy = R[1] * rx + R[4] * ry + R[7] * rz;
    float dz = R[2] * rx + R[5] * ry + R[8] * rz;
    float ss = dx * dx;
    ss = ss + dy * dy;
    ss = ss + dz * dz;
    float nrm = sqrtf(ss);
    dx = dx / nrm; dy = dy / nrm; dz = dz / nrm;

    float t1x = (-1.0f - cpx) / dx, t2x = (1.0f - cpx) / dx;
    float t1y = (-1.0f - cpy) / dy, t2y = (1.0f - cpy) / dy;
    float t1z = (-1.0f - cpz) / dz, t2z = (1.0f - cpz) / dz;
    float tmin = fmaxf(fminf(t1x, t2x), fmaxf(fminf(t1y, t2y), fminf(t1z, t2z)));
    float tmax = fminf(fmaxf(t1x, t2x), fminf(fmaxf(t1y, t2y), fmaxf(t1z, t2z)));
    bool hit = tmin < tmax;
    float t0 = fmaxf(hit ? tmin : 0.0f, 0.0f);

    float posx = cpx + dx * t0;
    float posy = cpy + dy * t0;
    float posz = cpz + dz * t0;
    float stx = dx * DT, sty = dy * DT, stz = dz * DT;

    // --- pre-loop (registers only): find contiguous valid range, exact pos sequence.
    // Per-axis positions are weakly monotone under repeated rounded adds, so the
    // valid set is a contiguous interval of step indices — identical to the
    // reference's per-step masked test.
    int n = 0;
    float e0x = 0.0f, e0y = 0.0f, e0z = 0.0f;
    {
        float sx = posx, sy = posy, sz = posz;
        int firstv = -1;
        for (int s = 0; s < NSTEPS; ++s) {
            bool valid = (sx > -1.0f) && (sx < 1.0f) &&
                         (sy > -1.0f) && (sy < 1.0f) &&
                         (sz > -1.0f) && (sz < 1.0f);
            if (valid) {
                if (firstv < 0) { firstv = s; e0x = sx; e0y = sy; e0z = sz; }
                n++;
            } else if (firstv >= 0) {
                break;  // convex volume: once exited, never valid again
            }
            sx = sx + stx; sy = sy + sty; sz = sz + stz;
        }
    }

    float accr = 0.0f, accg = 0.0f, accb = 0.0f, alpha = 0.0f;
    float gmax = (float)(D - 1);
    int zstride = D * D;
    int spatial = zstride * D;
    const float4* v4b = vol4 + (long)b * spatial;

    if (n > 0) {
        float pxx = e0x, pyy = e0y, pzz = e0z;
        float fxA, fyA, fzA, fxB = 0.f, fyB = 0.f, fzB = 0.f;
        float4 A[8], Bv[8];

        int baseA = voxel_base(pxx, pyy, pzz, D, gmax, zstride, fxA, fyA, fzA);
        load8(v4b, baseA, D, zstride, A);
        pxx = pxx + stx; pyy = pyy + sty; pzz = pzz + stz;

        if (n > 1) {
            int baseB = voxel_base(pxx, pyy, pzz, D, gmax, zstride, fxB, fyB, fzB);
            load8(v4b, baseB, D, zstride, Bv);
            pxx = pxx + stx; pyy = pyy + sty; pzz = pzz + stz;
        }

        int i = 0;
        for (; i + 2 < n; i += 2) {
            // consume step i (A), then speculatively prefetch step i+2 into A.
            accum_step(A, fxA, fyA, fzA, accr, accg, accb, alpha);
            int baseA2 = voxel_base(pxx, pyy, pzz, D, gmax, zstride, fxA, fyA, fzA);
            load8(v4b, baseA2, D, zstride, A);
            pxx = pxx + stx; pyy = pyy + sty; pzz = pzz + stz;

            // consume step i+1 (B), prefetch step i+3 into B (clamped => in-bounds
            // even when speculation runs past the exit face).
            accum_step(Bv, fxB, fyB, fzB, accr, accg, accb, alpha);
            int baseB2 = voxel_base(pxx, pyy, pzz, D, gmax, zstride, fxB, fyB, fzB);
            load8(v4b, baseB2, D, zstride, Bv);
            pxx = pxx + stx; pyy = pyy + sty; pzz = pzz + stz;
        }
        if (i < n) { accum_step(A, fxA, fyA, fzA, accr, accg, accb, alpha); i++; }
        if (i < n) { accum_step(Bv, fxB, fyB, fzB, accr, accg, accb, alpha); }
    }

    long hw = (long)H * W;
    long o = (long)b * 4 * hw + (long)y * W + x;
    out[o] = accr;
    out[o + hw] = accg;
    out[o + 2 * hw] = accb;
    out[o + 3 * hw] = alpha;
}

// Fallback (unpacked volume): original correctness-first version.
__global__ __launch_bounds__(256) void raymarch_simple_kernel(
        const float* __restrict__ camrot, const float* __restrict__ campos,
        const float* __restrict__ focal, const float* __restrict__ princpt,
        const float* __restrict__ pixelcoords, const float* __restrict__ vol,
        float* __restrict__ out, int B, int H, int W, int D) {
#pragma clang fp contract(off)
    int x = blockIdx.x * blockDim.x + threadIdx.x;
    int y = blockIdx.y * blockDim.y + threadIdx.y;
    int b = blockIdx.z;
    if (x >= W || y >= H) return;

    long pidx = (((long)b * H + y) * W + x) * 2;
    float px = pixelcoords[pidx];
    float py = pixelcoords[pidx + 1];
    const float* R = camrot + b * 9;
    float cpx = campos[b * 3 + 0], cpy = campos[b * 3 + 1], cpz = campos[b * 3 + 2];
    float flx = focal[b * 2 + 0], fly = focal[b * 2 + 1];
    float prx = princpt[b * 2 + 0], pry = princpt[b * 2 + 1];

    float rx = (px - prx) / flx;
    float ry = (py - pry) / fly;
    float rz = 1.0f;
    float dx = R[0] * rx + R[3] * ry + R[6] * rz;
    float dy = R[1] * rx + R[4] * ry + R[7] * rz;
    float dz = R[2] * rx + R[5] * ry + R[8] * rz;
    float ss = dx * dx;
    ss = ss + dy * dy;
    ss = ss + dz * dz;
    float nrm = sqrtf(ss);
    dx = dx / nrm; dy = dy / nrm; dz = dz / nrm;

    float t1x = (-1.0f - cpx) / dx, t2x = (1.0f - cpx) / dx;
    float t1y = (-1.0f - cpy) / dy, t2y = (1.0f - cpy) / dy;
    float t1z = (-1.0f - cpz) / dz, t2z = (1.0f - cpz) / dz;
    float tmin = fmaxf(fminf(t1x, t2x), fmaxf(fminf(t1y, t2y), fminf(t1z, t2z)));
    float tmax = fminf(fmaxf(t1x, t2x), fminf(fmaxf(t1y, t2y), fmaxf(t1z, t2z)));
    bool hit = tmin < tmax;
    float t0 = fmaxf(hit ? tmin : 0.0f, 0.0f);

    float posx = cpx + dx * t0;
    float posy = cpy + dy * t0;
    float posz = cpz + dz * t0;
    float stx = dx * DT, sty = dy * DT, stz = dz * DT;

    float accr = 0.0f, accg = 0.0f, accb = 0.0f, alpha = 0.0f;
    float gmax = (float)(D - 1);
    long spatial = (long)D * D * D;
    long zstride = (long)D * D;
    const float* vb = vol + (long)b * 4 * spatial;

    bool entered = false;
    for (int s = 0; s < NSTEPS; ++s) {
        bool valid = (posx > -1.0f) && (posx < 1.0f) &&
                     (posy > -1.0f) && (posy < 1.0f) &&
                     (posz > -1.0f) && (posz < 1.0f);
        if (valid) {
            entered = true;
            float gx = fminf(fmaxf((posx + 1.0f) * 0.5f * gmax, 0.0f), gmax);
            float gy = fminf(fmaxf((posy + 1.0f) * 0.5f * gmax, 0.0f), gmax);
            float gz = fminf(fmaxf((posz + 1.0f) * 0.5f * gmax, 0.0f), gmax);
            int ix0 = (int)floorf(gx); if (ix0 > D - 2) ix0 = D - 2;
            int iy0 = (int)floorf(gy); if (iy0 > D - 2) iy0 = D - 2;
            int iz0 = (int)floorf(gz); if (iz0 > D - 2) iz0 = D - 2;
            float fx = gx - (float)ix0;
            float fy = gy - (float)iy0;
            float fz = gz - (float)iz0;

            long s000 = (long)iz0 * zstride + (long)iy0 * D + ix0;
            float4 c000, c001, c010, c011, c100, c101, c110, c111;
            #define FETCH(dst, off) { long o_ = (off); \
                dst.x = vb[o_]; dst.y = vb[o_ + spatial]; \
                dst.z = vb[o_ + 2 * spatial]; dst.w = vb[o_ + 3 * spatial]; }
            FETCH(c000, s000);
            FETCH(c001, s000 + 1);
            FETCH(c010, s000 + D);
            FETCH(c011, s000 + D + 1);
            FETCH(c100, s000 + zstride);
            FETCH(c101, s000 + zstride + 1);
            FETCH(c110, s000 + zstride + D);
            FETCH(c111, s000 + zstride + D + 1);
            #undef FETCH
            float4 c00 = lerp4(c000, c001, fx);
            float4 c01 = lerp4(c010, c011, fx);
            float4 c10 = lerp4(c100, c101, fx);
            float4 c11 = lerp4(c110, c111, fx);
            float4 c0 = lerp4(c00, c01, fy);
            float4 c1 = lerp4(c10, c11, fy);
            float4 samp = lerp4(c0, c1, fz);

            float contrib = fminf(alpha + samp.w * DT, 1.0f) - alpha;
            accr = accr + samp.x * contrib;
            accg = accg + samp.y * contrib;
            accb = accb + samp.z * contrib;
            alpha = alpha + contrib;
            if (alpha >= 1.0f) break;
        } else if (entered) {
            break;
        }
        posx = posx + stx; posy = posy + sty; posz = posz + stz;
    }

    long hw = (long)H * W;
    long o = (long)b * 4 * hw + (long)y * W + x;
    out[o] = accr;
    out[o + hw] = accg;
    out[o + 2 * hw] = accb;
    out[o + 3 * hw] = alpha;
}

extern "C" void kernel_launch(void* const* d_in, const int* in_sizes, int n_in,
                              void* d_out, int out_size, void* d_ws, size_t ws_size,
                              hipStream_t stream) {
    const float* camrot = (const float*)d_in[0];
    const float* campos = (const float*)d_in[1];
    const float* focal = (const float*)d_in[2];
    const float* princpt = (const float*)d_in[3];
    const float* pixelcoords = (const float*)d_in[4];
    const float* volume = (const float*)d_in[5];
    float* out = (float*)d_out;

    int B = in_sizes[0] / 9;
    long spatial = (long)in_sizes[5] / (B * 4);  // D^3
    int D = (int)lround(cbrt((double)spatial));
    while ((long)D * D * D > spatial) D--;
    while ((long)(D + 1) * (D + 1) * (D + 1) <= spatial) D++;
    long hw = (long)in_sizes[4] / (B * 2);
    int H = (int)lround(sqrt((double)hw));
    int W = H;

    size_t need = (size_t)B * spatial * 4 * sizeof(float);
    dim3 blk(16, 16, 1);
    dim3 grd((W + 15) / 16, (H + 15) / 16, B);

    if (ws_size >= need) {
        if ((spatial & 3) == 0) {
            long nq = spatial >> 2;
            dim3 rgrd((unsigned)((nq + 255) / 256), B, 1);
            repack4_kernel<<<rgrd, dim3(256), 0, stream>>>(volume, (float4*)d_ws, spatial);
        } else {
            long total = (long)B * spatial;
            repack_kernel<<<dim3((unsigned)((total + 255) / 256)), dim3(256), 0, stream>>>(
                volume, (float4*)d_ws, total, spatial);
        }
        raymarch_pipe_kernel<<<grd, blk, 0, stream>>>(camrot, campos, focal, princpt,
                                                      pixelcoords, (const float4*)d_ws,
                                                      out, B, H, W, D);
    } else {
        raymarch_simple_kernel<<<grd, blk, 0, stream>>>(camrot, campos, focal, princpt,
                                                        pixelcoords, volume,
                                                        out, B, H, W, D);
    }
}

// Round 4
// 162.855 us; speedup vs baseline: 1.0136x; 1.0136x over previous
//
#include <hip/hip_runtime.h>
#include <math.h>

// Bit-exact replication of the numpy fp32 reference requires mul/add with
// separate rounding (no FMA contraction): the entry-face validity test
// (pos > -1) is knife-edge for every hitting ray.
#pragma clang fp contract(off)

#define DT 0.03125f
#define INV_DT 32.0f
#define NSTEPS 111

__device__ __forceinline__ float4 lerp4(float4 a, float4 b, float w) {
#pragma clang fp contract(off)
    float wa = 1.0f - w;
    float4 r;
    r.x = a.x * wa + b.x * w;
    r.y = a.y * wa + b.y * w;
    r.z = a.z * wa + b.z * w;
    r.w = a.w * wa + b.w * w;
    return r;
}

// ---------------- repack: [B,4,D,H,W] -> [B,D,H,W,4] ----------------

__global__ __launch_bounds__(256) void repack4_kernel(const float* __restrict__ vol,
                                                      float4* __restrict__ out,
                                                      long spatial) {
    long q = (long)blockIdx.x * blockDim.x + threadIdx.x;
    long nq = spatial >> 2;
    if (q >= nq) return;
    long b = blockIdx.y;
    const float* p = vol + b * 4 * spatial + (q << 2);
    float4 c0 = *(const float4*)(p);
    float4 c1 = *(const float4*)(p + spatial);
    float4 c2 = *(const float4*)(p + 2 * spatial);
    float4 c3 = *(const float4*)(p + 3 * spatial);
    float4* o = out + b * spatial + (q << 2);
    o[0] = make_float4(c0.x, c1.x, c2.x, c3.x);
    o[1] = make_float4(c0.y, c1.y, c2.y, c3.y);
    o[2] = make_float4(c0.z, c1.z, c2.z, c3.z);
    o[3] = make_float4(c0.w, c1.w, c2.w, c3.w);
}

__global__ __launch_bounds__(256) void repack_kernel(const float* __restrict__ vol,
                                                     float4* __restrict__ out,
                                                     long total, long spatial) {
    long idx = (long)blockIdx.x * blockDim.x + threadIdx.x;
    if (idx >= total) return;
    long b = idx / spatial;
    long s = idx - b * spatial;
    const float* p = vol + b * 4 * spatial + s;
    float4 v;
    v.x = p[0];
    v.y = p[spatial];
    v.z = p[2 * spatial];
    v.w = p[3 * spatial];
    out[idx] = v;
}

// ---------------- ray march ----------------

__device__ __forceinline__ void accum_step(const float4* c, float fx, float fy, float fz,
                                           float m, float& accr, float& accg,
                                           float& accb, float& alpha) {
#pragma clang fp contract(off)
    float4 c00 = lerp4(c[0], c[1], fx);
    float4 c01 = lerp4(c[2], c[3], fx);
    float4 c10 = lerp4(c[4], c[5], fx);
    float4 c11 = lerp4(c[6], c[7], fx);
    float4 c0 = lerp4(c00, c01, fy);
    float4 c1 = lerp4(c10, c11, fy);
    float4 samp = lerp4(c0, c1, fz);
    // reference: contrib = (min(alpha + sigma*DT, 1) - alpha) * valid
    float contrib = (fminf(alpha + samp.w * DT, 1.0f) - alpha) * m;
    accr = accr + samp.x * contrib;
    accg = accg + samp.y * contrib;
    accb = accb + samp.z * contrib;
    alpha = alpha + contrib;
}

// Branch-free masked march (mask semantics identical to the reference's
// `contrib * valid`), 4-stage software pipeline: 32 float4 gathers in flight.
template <int DD>
__global__ __launch_bounds__(64, 2) void raymarch_pipe_kernel(
        const float* __restrict__ camrot, const float* __restrict__ campos,
        const float* __restrict__ focal, const float* __restrict__ princpt,
        const float* __restrict__ pixelcoords, const float4* __restrict__ vol4,
        float* __restrict__ out, int B, int H, int W, int Drt) {
#pragma clang fp contract(off)
    const int D = (DD > 0) ? DD : Drt;
    int x = blockIdx.x * 16 + threadIdx.x;
    int y = blockIdx.y * 4 + threadIdx.y;
    int b = blockIdx.z;
    if (x >= W || y >= H) return;

    long pidx = (((long)b * H + y) * W + x) * 2;
    float px = pixelcoords[pidx];
    float py = pixelcoords[pidx + 1];
    const float* R = camrot + b * 9;
    float cpx = campos[b * 3 + 0], cpy = campos[b * 3 + 1], cpz = campos[b * 3 + 2];
    float flx = focal[b * 2 + 0], fly = focal[b * 2 + 1];
    float prx = princpt[b * 2 + 0], pry = princpt[b * 2 + 1];

    float rx = (px - prx) / flx;
    float ry = (py - pry) / fly;
    float rz = 1.0f;
    float dx = R[0] * rx + R[3] * ry + R[6] * rz;
    float dy = R[1] * rx + R[4] * ry + R[7] * rz;
    float dz = R[2] * rx + R[5] * ry + R[8] * rz;
    float ss = dx * dx;
    ss = ss + dy * dy;
    ss = ss + dz * dz;
    float nrm = sqrtf(ss);
    dx = dx / nrm; dy = dy / nrm; dz = dz / nrm;

    float t1x = (-1.0f - cpx) / dx, t2x = (1.0f - cpx) / dx;
    float t1y = (-1.0f - cpy) / dy, t2y = (1.0f - cpy) / dy;
    float t1z = (-1.0f - cpz) / dz, t2z = (1.0f - cpz) / dz;
    float tmin = fmaxf(fminf(t1x, t2x), fmaxf(fminf(t1y, t2y), fminf(t1z, t2z)));
    float tmax = fminf(fmaxf(t1x, t2x), fminf(fmaxf(t1y, t2y), fmaxf(t1z, t2z)));
    bool hit = tmin < tmax;
    float t0 = fmaxf(hit ? tmin : 0.0f, 0.0f);

    float posx = cpx + dx * t0;
    float posy = cpy + dy * t0;
    float posz = cpz + dz * t0;
    float stx = dx * DT, sty = dy * DT, stz = dz * DT;

    // Conservative bound on the last possibly-valid step: valid requires
    // t < tmax; +4 slack dwarfs fp drift over <=111 rounded adds. Steps in
    // [n, NSTEPS) are provably invalid (mask would be 0), so skipping them
    // is bit-exact. NaN span -> fminf picks NSTEPS (safe, conservative).
    float span = (tmax - t0) * INV_DT + 4.0f;
    span = fminf(span, (float)NSTEPS);
    int n = (hit && span > 0.0f) ? (int)span : 0;

    float accr = 0.0f, accg = 0.0f, accb = 0.0f, alpha = 0.0f;
    float gmax = (float)(D - 1);
    const int zstride = D * D;
    const float4* v4b = vol4 + (long)b * ((long)zstride * D);

    if (n > 0) {
        float pxx = posx, pyy = posy, pzz = posz;
        int spf = 0;  // step id of the next prefetch
        float4 C0[8], C1[8], C2[8], C3[8];
        float f0x, f0y, f0z, m0, f1x, f1y, f1z, m1;
        float f2x, f2y, f2z, m2, f3x, f3y, f3z, m3;

#define PREFETCH(CC, FX, FY, FZ, M) do {                                        \
        bool inside = (pxx > -1.0f) && (pxx < 1.0f) && (pyy > -1.0f) &&         \
                      (pyy < 1.0f) && (pzz > -1.0f) && (pzz < 1.0f);            \
        M = (inside && (spf < NSTEPS)) ? 1.0f : 0.0f;                           \
        float gx = fminf(fmaxf((pxx + 1.0f) * 0.5f * gmax, 0.0f), gmax);        \
        float gy = fminf(fmaxf((pyy + 1.0f) * 0.5f * gmax, 0.0f), gmax);        \
        float gz = fminf(fmaxf((pzz + 1.0f) * 0.5f * gmax, 0.0f), gmax);        \
        int ix0 = (int)floorf(gx); if (ix0 > D - 2) ix0 = D - 2;                \
        int iy0 = (int)floorf(gy); if (iy0 > D - 2) iy0 = D - 2;                \
        int iz0 = (int)floorf(gz); if (iz0 > D - 2) iz0 = D - 2;                \
        FX = gx - (float)ix0; FY = gy - (float)iy0; FZ = gz - (float)iz0;       \
        int base = iz0 * zstride + iy0 * D + ix0;                               \
        CC[0] = v4b[base];                CC[1] = v4b[base + 1];                \
        CC[2] = v4b[base + D];            CC[3] = v4b[base + D + 1];            \
        CC[4] = v4b[base + zstride];      CC[5] = v4b[base + zstride + 1];      \
        CC[6] = v4b[base + zstride + D];  CC[7] = v4b[base + zstride + D + 1];  \
        pxx = pxx + stx; pyy = pyy + sty; pzz = pzz + stz;                      \
        spf = spf + 1;                                                          \
    } while (0)

        PREFETCH(C0, f0x, f0y, f0z, m0);
        PREFETCH(C1, f1x, f1y, f1z, m1);
        PREFETCH(C2, f2x, f2y, f2z, m2);
        PREFETCH(C3, f3x, f3y, f3z, m3);

        int iters = (n + 3) >> 2;  // over-consume up to 3 masked steps: adds exact 0.0
        for (int it = 0; it < iters; ++it) {
            accum_step(C0, f0x, f0y, f0z, m0, accr, accg, accb, alpha);
            PREFETCH(C0, f0x, f0y, f0z, m0);
            accum_step(C1, f1x, f1y, f1z, m1, accr, accg, accb, alpha);
            PREFETCH(C1, f1x, f1y, f1z, m1);
            accum_step(C2, f2x, f2y, f2z, m2, accr, accg, accb, alpha);
            PREFETCH(C2, f2x, f2y, f2z, m2);
            accum_step(C3, f3x, f3y, f3z, m3, accr, accg, accb, alpha);
            PREFETCH(C3, f3x, f3y, f3z, m3);
        }
#undef PREFETCH
    }

    long hw = (long)H * W;
    long o = (long)b * 4 * hw + (long)y * W + x;
    out[o] = accr;
    out[o + hw] = accg;
    out[o + 2 * hw] = accb;
    out[o + 3 * hw] = alpha;
}

// Fallback (unpacked volume): correctness-first version.
__global__ __launch_bounds__(256) void raymarch_simple_kernel(
        const float* __restrict__ camrot, const float* __restrict__ campos,
        const float* __restrict__ focal, const float* __restrict__ princpt,
        const float* __restrict__ pixelcoords, const float* __restrict__ vol,
        float* __restrict__ out, int B, int H, int W, int D) {
#pragma clang fp contract(off)
    int x = blockIdx.x * blockDim.x + threadIdx.x;
    int y = blockIdx.y * blockDim.y + threadIdx.y;
    int b = blockIdx.z;
    if (x >= W || y >= H) return;

    long pidx = (((long)b * H + y) * W + x) * 2;
    float px = pixelcoords[pidx];
    float py = pixelcoords[pidx + 1];
    const float* R = camrot + b * 9;
    float cpx = campos[b * 3 + 0], cpy = campos[b * 3 + 1], cpz = campos[b * 3 + 2];
    float flx = focal[b * 2 + 0], fly = focal[b * 2 + 1];
    float prx = princpt[b * 2 + 0], pry = princpt[b * 2 + 1];

    float rx = (px - prx) / flx;
    float ry = (py - pry) / fly;
    float rz = 1.0f;
    float dx = R[0] * rx + R[3] * ry + R[6] * rz;
    float dy = R[1] * rx + R[4] * ry + R[7] * rz;
    float dz = R[2] * rx + R[5] * ry + R[8] * rz;
    float ss = dx * dx;
    ss = ss + dy * dy;
    ss = ss + dz * dz;
    float nrm = sqrtf(ss);
    dx = dx / nrm; dy = dy / nrm; dz = dz / nrm;

    float t1x = (-1.0f - cpx) / dx, t2x = (1.0f - cpx) / dx;
    float t1y = (-1.0f - cpy) / dy, t2y = (1.0f - cpy) / dy;
    float t1z = (-1.0f - cpz) / dz, t2z = (1.0f - cpz) / dz;
    float tmin = fmaxf(fminf(t1x, t2x), fmaxf(fminf(t1y, t2y), fminf(t1z, t2z)));
    float tmax = fminf(fmaxf(t1x, t2x), fminf(fmaxf(t1y, t2y), fmaxf(t1z, t2z)));
    bool hit = tmin < tmax;
    float t0 = fmaxf(hit ? tmin : 0.0f, 0.0f);

    float posx = cpx + dx * t0;
    float posy = cpy + dy * t0;
    float posz = cpz + dz * t0;
    float stx = dx * DT, sty = dy * DT, stz = dz * DT;

    float accr = 0.0f, accg = 0.0f, accb = 0.0f, alpha = 0.0f;
    float gmax = (float)(D - 1);
    long spatial = (long)D * D * D;
    long zstride = (long)D * D;
    const float* vb = vol + (long)b * 4 * spatial;

    bool entered = false;
    for (int s = 0; s < NSTEPS; ++s) {
        bool valid = (posx > -1.0f) && (posx < 1.0f) &&
                     (posy > -1.0f) && (posy < 1.0f) &&
                     (posz > -1.0f) && (posz < 1.0f);
        if (valid) {
            entered = true;
            float gx = fminf(fmaxf((posx + 1.0f) * 0.5f * gmax, 0.0f), gmax);
            float gy = fminf(fmaxf((posy + 1.0f) * 0.5f * gmax, 0.0f), gmax);
            float gz = fminf(fmaxf((posz + 1.0f) * 0.5f * gmax, 0.0f), gmax);
            int ix0 = (int)floorf(gx); if (ix0 > D - 2) ix0 = D - 2;
            int iy0 = (int)floorf(gy); if (iy0 > D - 2) iy0 = D - 2;
            int iz0 = (int)floorf(gz); if (iz0 > D - 2) iz0 = D - 2;
            float fx = gx - (float)ix0;
            float fy = gy - (float)iy0;
            float fz = gz - (float)iz0;

            long s000 = (long)iz0 * zstride + (long)iy0 * D + ix0;
            float4 c000, c001, c010, c011, c100, c101, c110, c111;
            #define FETCH(dst, off) { long o_ = (off); \
                dst.x = vb[o_]; dst.y = vb[o_ + spatial]; \
                dst.z = vb[o_ + 2 * spatial]; dst.w = vb[o_ + 3 * spatial]; }
            FETCH(c000, s000);
            FETCH(c001, s000 + 1);
            FETCH(c010, s000 + D);
            FETCH(c011, s000 + D + 1);
            FETCH(c100, s000 + zstride);
            FETCH(c101, s000 + zstride + 1);
            FETCH(c110, s000 + zstride + D);
            FETCH(c111, s000 + zstride + D + 1);
            #undef FETCH
            float4 c00 = lerp4(c000, c001, fx);
            float4 c01 = lerp4(c010, c011, fx);
            float4 c10 = lerp4(c100, c101, fx);
            float4 c11 = lerp4(c110, c111, fx);
            float4 c0 = lerp4(c00, c01, fy);
            float4 c1 = lerp4(c10, c11, fy);
            float4 samp = lerp4(c0, c1, fz);

            float contrib = fminf(alpha + samp.w * DT, 1.0f) - alpha;
            accr = accr + samp.x * contrib;
            accg = accg + samp.y * contrib;
            accb = accb + samp.z * contrib;
            alpha = alpha + contrib;
            if (alpha >= 1.0f) break;
        } else if (entered) {
            break;
        }
        posx = posx + stx; posy = posy + sty; posz = posz + stz;
    }

    long hw = (long)H * W;
    long o = (long)b * 4 * hw + (long)y * W + x;
    out[o] = accr;
    out[o + hw] = accg;
    out[o + 2 * hw] = accb;
    out[o + 3 * hw] = alpha;
}

extern "C" void kernel_launch(void* const* d_in, const int* in_sizes, int n_in,
                              void* d_out, int out_size, void* d_ws, size_t ws_size,
                              hipStream_t stream) {
    const float* camrot = (const float*)d_in[0];
    const float* campos = (const float*)d_in[1];
    const float* focal = (const float*)d_in[2];
    const float* princpt = (const float*)d_in[3];
    const float* pixelcoords = (const float*)d_in[4];
    const float* volume = (const float*)d_in[5];
    float* out = (float*)d_out;

    int B = in_sizes[0] / 9;
    long spatial = (long)in_sizes[5] / (B * 4);  // D^3
    int D = (int)lround(cbrt((double)spatial));
    while ((long)D * D * D > spatial) D--;
    while ((long)(D + 1) * (D + 1) * (D + 1) <= spatial) D++;
    long hw = (long)in_sizes[4] / (B * 2);
    int H = (int)lround(sqrt((double)hw));
    int W = H;

    size_t need = (size_t)B * spatial * 4 * sizeof(float);

    if (ws_size >= need) {
        if ((spatial & 3) == 0) {
            long nq = spatial >> 2;
            dim3 rgrd((unsigned)((nq + 255) / 256), B, 1);
            repack4_kernel<<<rgrd, dim3(256), 0, stream>>>(volume, (float4*)d_ws, spatial);
        } else {
            long total = (long)B * spatial;
            repack_kernel<<<dim3((unsigned)((total + 255) / 256)), dim3(256), 0, stream>>>(
                volume, (float4*)d_ws, total, spatial);
        }
        dim3 blk(16, 4, 1);
        dim3 grd((W + 15) / 16, (H + 3) / 4, B);
        if (D == 128) {
            raymarch_pipe_kernel<128><<<grd, blk, 0, stream>>>(
                camrot, campos, focal, princpt, pixelcoords, (const float4*)d_ws,
                out, B, H, W, D);
        } else {
            raymarch_pipe_kernel<0><<<grd, blk, 0, stream>>>(
                camrot, campos, focal, princpt, pixelcoords, (const float4*)d_ws,
                out, B, H, W, D);
        }
    } else {
        dim3 blk(16, 16, 1);
        dim3 grd((W + 15) / 16, (H + 15) / 16, B);
        raymarch_simple_kernel<<<grd, blk, 0, stream>>>(camrot, campos, focal, princpt,
                                                        pixelcoords, volume,
                                                        out, B, H, W, D);
    }
}